// Round 3
// baseline (240.464 us; speedup 1.0000x reference)
//
#include <hip/hip_runtime.h>

// out[i] = image[i*3 + 0] * w[i*16 + 15], i in [0, 4096*4096)
//
// 8 outputs per thread:
//   image: 6x float4 contiguous loads (t*96 bytes, 16B-aligned)
//   w:     8x scalar loads, single base + folded offset immediates (k*64)
//   out:   2x 16B nontemporal stores (write-once data, skip L2 pollution)
// Traffic floor: 201MB (img) + 1074MB (w sectors) + 67MB (out) = 1.342 GB.

typedef float f32x4 __attribute__((ext_vector_type(4)));

__global__ __launch_bounds__(256) void MyLayer_kernel(
    const f32x4* __restrict__ img4,
    const float* __restrict__ w,
    f32x4*       __restrict__ out4)
{
    const size_t t  = (size_t)blockIdx.x * blockDim.x + threadIdx.x;
    const size_t ib = t * 6;               // 8 outputs * 3 ch = 24 floats = 6 float4

    // image bytes [t*96, t*96+96): channel-0 at float positions 0,3,6,9,12,15,18,21
    const f32x4 a0 = img4[ib + 0];
    const f32x4 a1 = img4[ib + 1];
    const f32x4 a2 = img4[ib + 2];
    const f32x4 a3 = img4[ib + 3];
    const f32x4 a4 = img4[ib + 4];
    const f32x4 a5 = img4[ib + 5];

    // w element (t*8+k)*16 + 15 = t*128 + 15 + k*16 ; byte offsets k*64 fold to imm
    const float* wp = w + t * 128 + 15;
    const float w0 = wp[0];
    const float w1 = wp[16];
    const float w2 = wp[32];
    const float w3 = wp[48];
    const float w4 = wp[64];
    const float w5 = wp[80];
    const float w6 = wp[96];
    const float w7 = wp[112];

    const float i0 = a0.x;   // (8t+0)*3
    const float i1 = a0.w;   // (8t+1)*3
    const float i2 = a1.z;   // (8t+2)*3
    const float i3 = a2.y;   // (8t+3)*3
    const float i4 = a3.x;   // (8t+4)*3
    const float i5 = a3.w;   // (8t+5)*3
    const float i6 = a4.z;   // (8t+6)*3
    const float i7 = a5.y;   // (8t+7)*3

    f32x4 o0; o0.x = i0 * w0; o0.y = i1 * w1; o0.z = i2 * w2; o0.w = i3 * w3;
    f32x4 o1; o1.x = i4 * w4; o1.y = i5 * w5; o1.z = i6 * w6; o1.w = i7 * w7;
    __builtin_nontemporal_store(o0, &out4[t * 2 + 0]);
    __builtin_nontemporal_store(o1, &out4[t * 2 + 1]);
}

extern "C" void kernel_launch(void* const* d_in, const int* in_sizes, int n_in,
                              void* d_out, int out_size, void* d_ws, size_t ws_size,
                              hipStream_t stream)
{
    const float* image = (const float*)d_in[0];  // (4096,4096,3) f32
    const float* w     = (const float*)d_in[1];  // (4096,4096,16) f32
    float*       out   = (float*)d_out;          // (4096,4096) f32

    const int n = 4096 * 4096;
    const int threads = 256;
    const int blocks  = n / 8 / threads;         // 8192, exact

    MyLayer_kernel<<<blocks, threads, 0, stream>>>(
        (const f32x4*)image, w, (f32x4*)out);
}